// Round 11
// baseline (357.689 us; speedup 1.0000x reference)
//
#include <hip/hip_runtime.h>

#define S_LEN 2048
#define DMODEL 1024
#define NH 16
#define NKVH 4
#define DKH 64
#define KVD 256
#define SCALE_LOG2E 0.18033688f  // (1/sqrt(64)) * log2(e)

typedef __bf16 bf16;
typedef bf16  bf16x8 __attribute__((ext_vector_type(8)));
typedef bf16  bf16x4 __attribute__((ext_vector_type(4)));
typedef float f32x4  __attribute__((ext_vector_type(4)));
typedef bf16x8 bf16x8_a __attribute__((may_alias));
typedef bf16x4 bf16x4_a __attribute__((may_alias));
typedef float f32x4g __attribute__((ext_vector_type(4), may_alias));

#define VWAIT(N)                                             \
    do {                                                     \
        asm volatile("s_waitcnt vmcnt(" #N ")" ::: "memory");\
        __builtin_amdgcn_sched_barrier(0);                   \
    } while (0)

// drain LDS ops then barrier: required when LDS WRITES/READS must order cross-wave
#define LGKM0_BARRIER()                                       \
    do {                                                      \
        asm volatile("s_waitcnt lgkmcnt(0)" ::: "memory");    \
        __builtin_amdgcn_sched_barrier(0);                    \
        __builtin_amdgcn_s_barrier();                         \
        __builtin_amdgcn_sched_barrier(0);                    \
    } while (0)

__device__ __forceinline__ void gll16(const bf16* g, bf16* l) {
    __builtin_amdgcn_global_load_lds(
        (const __attribute__((address_space(1))) void*)g,
        (__attribute__((address_space(3))) void*)l, 16, 0, 0);
}

// ---------------- fused fp32 -> bf16 casts ----------------
__global__ __launch_bounds__(256) void cast3_bf16(const float* __restrict__ a,
                                                  const float* __restrict__ b,
                                                  const float* __restrict__ c,
                                                  bf16* __restrict__ oa, bf16* __restrict__ ob,
                                                  bf16* __restrict__ oc, int n4) {
    const float* src = blockIdx.y == 0 ? a : blockIdx.y == 1 ? b : c;
    bf16* dst = blockIdx.y == 0 ? oa : blockIdx.y == 1 ? ob : oc;
    int stride = gridDim.x * blockDim.x;
    for (int i = blockIdx.x * blockDim.x + threadIdx.x; i < n4; i += stride) {
        f32x4g v = ((const f32x4g*)src)[i];
        bf16x4 o;
        o[0] = (bf16)v[0]; o[1] = (bf16)v[1]; o[2] = (bf16)v[2]; o[3] = (bf16)v[3];
        ((bf16x4*)dst)[i] = o;
    }
}

__global__ __launch_bounds__(256) void cast2_bf16(const float* __restrict__ a,
                                                  const float* __restrict__ b,
                                                  bf16* __restrict__ oa, bf16* __restrict__ ob,
                                                  int n4) {
    const float* src = blockIdx.y == 0 ? a : b;
    bf16* dst = blockIdx.y == 0 ? oa : ob;
    int stride = gridDim.x * blockDim.x;
    for (int i = blockIdx.x * blockDim.x + threadIdx.x; i < n4; i += stride) {
        f32x4g v = ((const f32x4g*)src)[i];
        bf16x4 o;
        o[0] = (bf16)v[0]; o[1] = (bf16)v[1]; o[2] = (bf16)v[2]; o[3] = (bf16)v[3];
        ((bf16x4*)dst)[i] = o;
    }
}

// ---------------- NT GEMM: C[m][n] = sum_k A[m][k]*Bw[n][k] + bias[n] ----------------
template <int OUTF32>
__global__ __launch_bounds__(256) void gemm_bt(const bf16* __restrict__ A,
                                               const bf16* __restrict__ Bw,
                                               const float* __restrict__ bias,
                                               void* __restrict__ Cout,
                                               int M, int N, int K) {
    __shared__ bf16 As[4096];  // 128 x 32
    __shared__ bf16 Bs[4096];
    const int bm = blockIdx.x, bn = blockIdx.y;
    const int tid = threadIdx.x, wave = tid >> 6, lane = tid & 63;
    const int l15 = lane & 15, lhi = lane >> 4;
    const int wr = (wave >> 1) * 64, wc = (wave & 1) * 64;
    f32x4 acc[4][4] = {};
    const size_t arow0 = (size_t)bm * 128 * K;
    const size_t brow0 = (size_t)bn * 128 * K;

    for (int kt = 0; kt < K; kt += 32) {
#pragma unroll
        for (int i = 0; i < 2; ++i) {
            int base = i * 2048 + wave * 512;
            int flat = base + lane * 8;
            int r = flat >> 5, c = flat & 31;
            gll16(A + arow0 + (size_t)r * K + kt + c, &As[base]);
            gll16(Bw + brow0 + (size_t)r * K + kt + c, &Bs[base]);
        }
        __syncthreads();
        bf16x8 af[4], bfr[4];
#pragma unroll
        for (int mi = 0; mi < 4; ++mi)
            af[mi] = *(const bf16x8_a*)&As[(wr + mi * 16 + l15) * 32 + lhi * 8];
#pragma unroll
        for (int ni = 0; ni < 4; ++ni)
            bfr[ni] = *(const bf16x8_a*)&Bs[(wc + ni * 16 + l15) * 32 + lhi * 8];
#pragma unroll
        for (int mi = 0; mi < 4; ++mi)
#pragma unroll
            for (int ni = 0; ni < 4; ++ni)
                acc[mi][ni] = __builtin_amdgcn_mfma_f32_16x16x32_bf16(
                    af[mi], bfr[ni], acc[mi][ni], 0, 0, 0);
        __syncthreads();
    }
#pragma unroll
    for (int mi = 0; mi < 4; ++mi)
#pragma unroll
        for (int ni = 0; ni < 4; ++ni)
#pragma unroll
            for (int j = 0; j < 4; ++j) {
                int row = bm * 128 + wr + mi * 16 + lhi * 4 + j;
                int col = bn * 128 + wc + ni * 16 + l15;
                float v = acc[mi][ni][j] + bias[col];
                if (OUTF32)
                    ((float*)Cout)[(size_t)row * N + col] = v;
                else
                    ((bf16*)Cout)[(size_t)row * N + col] = (bf16)v;
            }
}

// ---------------- V transpose: Vp[b*2048+s][g*64+d] -> VT[b][g][d][s] ----------------
__global__ __launch_bounds__(256) void vtrans(const bf16* __restrict__ V,
                                              bf16* __restrict__ VT) {
    __shared__ bf16 t[64][65];
    const int s0 = blockIdx.x * 64;
    const int bg = blockIdx.y;
    const int b = bg >> 2, g = bg & 3;
#pragma unroll
    for (int i = 0; i < 16; ++i) {
        int flat = threadIdx.x + i * 256;
        int r = flat >> 6, c = flat & 63;
        t[c][r] = V[(size_t)(b * S_LEN + s0 + r) * KVD + g * DKH + c];
    }
    __syncthreads();
#pragma unroll
    for (int i = 0; i < 16; ++i) {
        int flat = threadIdx.x + i * 256;
        int d = flat >> 6, si = flat & 63;
        VT[((size_t)bg * DKH + d) * S_LEN + s0 + si] = t[d][si];
    }
}

// ---------------- merged attention v2 ----------------
// grid 2048 (XCD-swizzled) = bh(32) x qt(64: 32 q-rows); block 512 = 8 waves (2 wq x 4 wk).
// Pass A: BARRIER-FREE denominators (direct global K fragment reads, waves free-run).
// Pass B: QK -> p=exp*rinv -> Pb(bf16) -> {PV} + {prob store: Pb re-read, widen to f32}.
// LDS 36 KB; __launch_bounds__(512,8) -> 4 blocks/CU (32 waves), grid = exactly 2 rounds.
__global__ __launch_bounds__(512, 8) void attn_all(const bf16* __restrict__ Qp,
                                                   const bf16* __restrict__ Kp,
                                                   const bf16* __restrict__ VT,
                                                   float* __restrict__ attn_out,
                                                   bf16* __restrict__ ctx) {
    __shared__ bf16 KV[4][4096];  // 32 KB: pass B K{0,1}, V{2,3}
    __shared__ bf16 Pb[2048];     // 4 KB [32 q][64 k] bf16 swizzled; head doubles as red[128] f32
    const int raw = blockIdx.x;
    const int wg = (raw & 7) * 256 + (raw >> 3);  // 2048 % 8 == 0: bijective
    const int bh = wg >> 6;
    const int qt = wg & 63;
    const int h = bh & (NH - 1), b = bh >> 4, g = h >> 2;
    const int tid = threadIdx.x, wave = tid >> 6, lane = tid & 63;
    const int l15 = lane & 15, lhi = lane >> 4;
    const int wq = wave >> 2, wk = wave & 3;  // wk doubles as dv-tile in PV
    const int qrow0 = qt * 32;
    const int sw = (l15 & 7) << 4;

    // Q fragments for this wave's 16 q-rows
    const bf16* qb =
        Qp + (size_t)(b * S_LEN + qrow0 + wq * 16 + l15) * DMODEL + h * DKH + lhi * 8;
    bf16x8 aq0 = *(const bf16x8_a*)qb;
    bf16x8 aq1 = *(const bf16x8_a*)(qb + 32);

    // pass-B staging geometry: thread -> (row tid>>3, 16B slot tid&7), source pre-swizzled
    const int srow = tid >> 3;
    const int scc = (tid & 7) ^ (srow & 7);
    const bf16* ksrc = Kp + (size_t)(b * S_LEN + srow) * KVD + g * DKH + scc * 8;
    const bf16* vsrc = VT + ((size_t)(b * NKVH + g) * DKH + srow) * S_LEN + scc * 8;

    // ================= pass A: barrier-free denominators =================
    // wave (wq,wk): keys c*64 + wk*16 + {A-frag rows}; direct global loads, no LDS.
    const bf16* ka = Kp + (size_t)(b * S_LEN + wk * 16 + l15) * KVD + g * DKH + lhi * 8;
    float lsum = 0.f;
    for (int c = 0; c < 32; ++c) {
        bf16x8 k0 = *(const bf16x8_a*)(ka + (size_t)c * 64 * KVD);
        bf16x8 k1 = *(const bf16x8_a*)(ka + (size_t)c * 64 * KVD + 32);
        f32x4 a = {0.f, 0.f, 0.f, 0.f};
        a = __builtin_amdgcn_mfma_f32_16x16x32_bf16(k0, aq0, a, 0, 0, 0);
        a = __builtin_amdgcn_mfma_f32_16x16x32_bf16(k1, aq1, a, 0, 0, 0);
        lsum += __builtin_exp2f(a[0] * SCALE_LOG2E) + __builtin_exp2f(a[1] * SCALE_LOG2E) +
                __builtin_exp2f(a[2] * SCALE_LOG2E) + __builtin_exp2f(a[3] * SCALE_LOG2E);
    }
    // reduce: lanes {l15, +16, +32, +48} share q = wq*16+l15
    lsum += __shfl_xor(lsum, 16, 64);
    lsum += __shfl_xor(lsum, 32, 64);

    // pass-B prologue staging: issued now, lands while we do the reduction barriers
    gll16(ksrc, &KV[0][wave * 512]);
    gll16(vsrc, &KV[2][wave * 512]);

    float* red = (float*)&Pb[0];  // 512 B scratch in Pb
    if (lane < 16) red[wave * 16 + lane] = lsum;
    LGKM0_BARRIER();  // red visible to all waves
    float lt = red[(wq * 4 + 0) * 16 + l15] + red[(wq * 4 + 1) * 16 + l15] +
               red[(wq * 4 + 2) * 16 + l15] + red[(wq * 4 + 3) * 16 + l15];
    const float rinv = 1.0f / lt;
    LGKM0_BARRIER();  // red reads drained before Pb is overwritten in pass B

    // ================= pass B: probs + PV (K,V ring-2) =================
    f32x4 cacc = {0.f, 0.f, 0.f, 0.f};
    float* arow = attn_out + ((size_t)bh * S_LEN + qrow0) * S_LEN;
    char* pbb = (char*)&Pb[0];
    const int ql = wq * 16 + l15;                         // q-local row this lane produces
    const int pbw = (ql * 128 + wk * 32 + lhi * 8) ^ sw;  // Pb write byte
    const int strow = tid >> 4;                           // 0..31 store row
    const int stslot = tid & 15;
    const int pbr = (strow * 128 + stslot * 8) ^ ((strow & 7) << 4);  // Pb read byte
    float* gst = arow + (size_t)strow * S_LEN + stslot * 4;

    for (int c = 0; c < 32; ++c) {
        // outstanding at this point (issue order): K(c), V(c), [store(c-1)]
        if (c == 0) { VWAIT(0); } else { VWAIT(1); }
        __builtin_amdgcn_s_barrier();  // K(c), V(c) resident for all waves
        // QK(c): S[key = c*64 + wk*16 + lhi*4 + j][q = wq*16 + l15]
        const char* kc = (const char*)&KV[c & 1][0];
        const int rb = (wk * 16 + l15) * 128;
        bf16x8 k0 = *(const bf16x8_a*)(kc + rb + ((lhi * 16) ^ sw));
        bf16x8 k1 = *(const bf16x8_a*)(kc + rb + ((lhi * 16 + 64) ^ sw));
        f32x4 a = {0.f, 0.f, 0.f, 0.f};
        __builtin_amdgcn_s_setprio(1);
        a = __builtin_amdgcn_mfma_f32_16x16x32_bf16(k0, aq0, a, 0, 0, 0);
        a = __builtin_amdgcn_mfma_f32_16x16x32_bf16(k1, aq1, a, 0, 0, 0);
        __builtin_amdgcn_s_setprio(0);
        bf16x4 pb4;
#pragma unroll
        for (int j = 0; j < 4; ++j)
            pb4[j] = (bf16)(__builtin_exp2f(a[j] * SCALE_LOG2E) * rinv);
        *(bf16x4_a*)(pbb + pbw) = pb4;
        LGKM0_BARRIER();  // P visible to all waves
        // restage: buffers (c+1)&1 were last read before the chunk-start barrier of c
        if (c < 31) {
            gll16(ksrc + (size_t)((c + 1) * 64) * KVD, &KV[(c + 1) & 1][wave * 512]);
            gll16(vsrc + (c + 1) * 64, &KV[2 + ((c + 1) & 1)][wave * 512]);
            __builtin_amdgcn_sched_barrier(0);  // keep prob store AFTER the gll16s
        }
        // prob store: re-read Pb row, widen bf16 -> f32, 256B-contig per 16-lane group
        bf16x4 pv4 = *(const bf16x4_a*)(pbb + pbr);
        f32x4 pf4;
#pragma unroll
        for (int j = 0; j < 4; ++j) pf4[j] = (float)pv4[j];
        *(f32x4g*)(gst + c * 64) = pf4;
        // PV(c): A = normalized P from Pb, B = V^T tile
        bf16x8 ap0 = *(const bf16x8_a*)(pbb + ((ql * 128 + lhi * 16) ^ sw));
        bf16x8 ap1 = *(const bf16x8_a*)(pbb + ((ql * 128 + 64 + lhi * 16) ^ sw));
        const char* vc = (const char*)&KV[2 + (c & 1)][0];
        const int vb = (wk * 16 + l15) * 128;
        bf16x8 v0 = *(const bf16x8_a*)(vc + vb + ((lhi * 16) ^ sw));
        bf16x8 v1 = *(const bf16x8_a*)(vc + vb + ((lhi * 16 + 64) ^ sw));
        __builtin_amdgcn_s_setprio(1);
        cacc = __builtin_amdgcn_mfma_f32_16x16x32_bf16(ap0, v0, cacc, 0, 0, 0);
        cacc = __builtin_amdgcn_mfma_f32_16x16x32_bf16(ap1, v1, cacc, 0, 0, 0);
        __builtin_amdgcn_s_setprio(0);
    }
    // ctx write: q = qrow0 + wq*16 + lhi*4 + j, dv = h*64 + wk*16 + l15 (P pre-normalized)
#pragma unroll
    for (int j = 0; j < 4; ++j) {
        int row = qrow0 + wq * 16 + lhi * 4 + j;
        ctx[(size_t)(b * S_LEN + row) * DMODEL + h * DKH + wk * 16 + l15] = (bf16)cacc[j];
    }
}

extern "C" void kernel_launch(void* const* d_in, const int* in_sizes, int n_in,
                              void* d_out, int out_size, void* d_ws, size_t ws_size,
                              hipStream_t stream) {
    const float* query = (const float*)d_in[0];
    const float* key_i = (const float*)d_in[1];
    const float* value = (const float*)d_in[2];
    const float* Wq = (const float*)d_in[3];
    const float* bq = (const float*)d_in[4];
    const float* Wk = (const float*)d_in[5];
    const float* bk = (const float*)d_in[6];
    const float* Wv = (const float*)d_in[7];
    const float* bv = (const float*)d_in[8];
    const float* Wo = (const float*)d_in[9];
    const float* bo = (const float*)d_in[10];

    char* ws = (char*)d_ws;
    bf16* qx = (bf16*)(ws + 0);
    bf16* kx = (bf16*)(ws + ((size_t)8 << 20));
    bf16* vx = (bf16*)(ws + ((size_t)16 << 20));
    bf16* wqx = (bf16*)(ws + ((size_t)32 << 20));
    bf16* wkx = (bf16*)(ws + ((size_t)34 << 20));
    bf16* wvx = (bf16*)(ws + ((size_t)34 << 20) + ((size_t)512 << 10));
    bf16* wox = (bf16*)(ws + ((size_t)35 << 20));
    bf16* Qp = (bf16*)(ws + ((size_t)37 << 20));
    bf16* Kp = (bf16*)(ws + ((size_t)45 << 20));
    bf16* Vp = (bf16*)(ws + ((size_t)47 << 20));
    bf16* VT = (bf16*)(ws + ((size_t)49 << 20));
    bf16* ctxb = (bf16*)(ws + ((size_t)51 << 20));

    const int BS = 2 * S_LEN;  // 4096 rows

    cast3_bf16<<<dim3(1024, 3), 256, 0, stream>>>(query, key_i, value, qx, kx, vx,
                                                  BS * DMODEL / 4);
    cast2_bf16<<<dim3(1024, 2), 256, 0, stream>>>(Wq, Wo, wqx, wox, DMODEL * DMODEL / 4);
    cast2_bf16<<<dim3(256, 2), 256, 0, stream>>>(Wk, Wv, wkx, wvx, KVD * DMODEL / 4);

    gemm_bt<0><<<dim3(32, 8), 256, 0, stream>>>(qx, wqx, bq, Qp, BS, DMODEL, DMODEL);
    gemm_bt<0><<<dim3(32, 2), 256, 0, stream>>>(kx, wkx, bk, Kp, BS, KVD, DMODEL);
    gemm_bt<0><<<dim3(32, 2), 256, 0, stream>>>(vx, wvx, bv, Vp, BS, KVD, DMODEL);

    vtrans<<<dim3(32, 8), 256, 0, stream>>>(Vp, VT);

    float* attn_out = (float*)d_out + (size_t)BS * DMODEL;
    attn_all<<<2048, 512, 0, stream>>>(Qp, Kp, VT, attn_out, ctxb);

    gemm_bt<1><<<dim3(32, 8), 256, 0, stream>>>(ctxb, wox, bo, (float*)d_out, BS, DMODEL, DMODEL);
}

// Round 12
// 293.946 us; speedup vs baseline: 1.2169x; 1.2169x over previous
//
#include <hip/hip_runtime.h>

#define S_LEN 2048
#define DMODEL 1024
#define NH 16
#define NKVH 4
#define DKH 64
#define KVD 256
#define SCALE_LOG2E 0.18033688f  // (1/sqrt(64)) * log2(e)

typedef __bf16 bf16;
typedef bf16  bf16x8 __attribute__((ext_vector_type(8)));
typedef bf16  bf16x4 __attribute__((ext_vector_type(4)));
typedef float f32x4  __attribute__((ext_vector_type(4)));
typedef bf16x8 bf16x8_a __attribute__((may_alias));
typedef bf16x4 bf16x4_a __attribute__((may_alias));
typedef float f32x4g __attribute__((ext_vector_type(4), may_alias));

#define VWAIT(N)                                             \
    do {                                                     \
        asm volatile("s_waitcnt vmcnt(" #N ")" ::: "memory");\
        __builtin_amdgcn_sched_barrier(0);                   \
    } while (0)

// drain LDS ops then barrier: required when LDS WRITES/READS must order cross-wave
#define LGKM0_BARRIER()                                       \
    do {                                                      \
        asm volatile("s_waitcnt lgkmcnt(0)" ::: "memory");    \
        __builtin_amdgcn_sched_barrier(0);                    \
        __builtin_amdgcn_s_barrier();                         \
        __builtin_amdgcn_sched_barrier(0);                    \
    } while (0)

__device__ __forceinline__ void gll16(const bf16* g, bf16* l) {
    __builtin_amdgcn_global_load_lds(
        (const __attribute__((address_space(1))) void*)g,
        (__attribute__((address_space(3))) void*)l, 16, 0, 0);
}

// ---------------- fused fp32 -> bf16 casts ----------------
__global__ __launch_bounds__(256) void cast3_bf16(const float* __restrict__ a,
                                                  const float* __restrict__ b,
                                                  const float* __restrict__ c,
                                                  bf16* __restrict__ oa, bf16* __restrict__ ob,
                                                  bf16* __restrict__ oc, int n4) {
    const float* src = blockIdx.y == 0 ? a : blockIdx.y == 1 ? b : c;
    bf16* dst = blockIdx.y == 0 ? oa : blockIdx.y == 1 ? ob : oc;
    int stride = gridDim.x * blockDim.x;
    for (int i = blockIdx.x * blockDim.x + threadIdx.x; i < n4; i += stride) {
        f32x4g v = ((const f32x4g*)src)[i];
        bf16x4 o;
        o[0] = (bf16)v[0]; o[1] = (bf16)v[1]; o[2] = (bf16)v[2]; o[3] = (bf16)v[3];
        ((bf16x4*)dst)[i] = o;
    }
}

__global__ __launch_bounds__(256) void cast2_bf16(const float* __restrict__ a,
                                                  const float* __restrict__ b,
                                                  bf16* __restrict__ oa, bf16* __restrict__ ob,
                                                  int n4) {
    const float* src = blockIdx.y == 0 ? a : b;
    bf16* dst = blockIdx.y == 0 ? oa : ob;
    int stride = gridDim.x * blockDim.x;
    for (int i = blockIdx.x * blockDim.x + threadIdx.x; i < n4; i += stride) {
        f32x4g v = ((const f32x4g*)src)[i];
        bf16x4 o;
        o[0] = (bf16)v[0]; o[1] = (bf16)v[1]; o[2] = (bf16)v[2]; o[3] = (bf16)v[3];
        ((bf16x4*)dst)[i] = o;
    }
}

// ---------------- NT GEMM: C[m][n] = sum_k A[m][k]*Bw[n][k] + bias[n] ----------------
template <int OUTF32>
__global__ __launch_bounds__(256) void gemm_bt(const bf16* __restrict__ A,
                                               const bf16* __restrict__ Bw,
                                               const float* __restrict__ bias,
                                               void* __restrict__ Cout,
                                               int M, int N, int K) {
    __shared__ bf16 As[4096];  // 128 x 32
    __shared__ bf16 Bs[4096];
    const int bm = blockIdx.x, bn = blockIdx.y;
    const int tid = threadIdx.x, wave = tid >> 6, lane = tid & 63;
    const int l15 = lane & 15, lhi = lane >> 4;
    const int wr = (wave >> 1) * 64, wc = (wave & 1) * 64;
    f32x4 acc[4][4] = {};
    const size_t arow0 = (size_t)bm * 128 * K;
    const size_t brow0 = (size_t)bn * 128 * K;

    for (int kt = 0; kt < K; kt += 32) {
#pragma unroll
        for (int i = 0; i < 2; ++i) {
            int base = i * 2048 + wave * 512;
            int flat = base + lane * 8;
            int r = flat >> 5, c = flat & 31;
            gll16(A + arow0 + (size_t)r * K + kt + c, &As[base]);
            gll16(Bw + brow0 + (size_t)r * K + kt + c, &Bs[base]);
        }
        __syncthreads();
        bf16x8 af[4], bfr[4];
#pragma unroll
        for (int mi = 0; mi < 4; ++mi)
            af[mi] = *(const bf16x8_a*)&As[(wr + mi * 16 + l15) * 32 + lhi * 8];
#pragma unroll
        for (int ni = 0; ni < 4; ++ni)
            bfr[ni] = *(const bf16x8_a*)&Bs[(wc + ni * 16 + l15) * 32 + lhi * 8];
#pragma unroll
        for (int mi = 0; mi < 4; ++mi)
#pragma unroll
            for (int ni = 0; ni < 4; ++ni)
                acc[mi][ni] = __builtin_amdgcn_mfma_f32_16x16x32_bf16(
                    af[mi], bfr[ni], acc[mi][ni], 0, 0, 0);
        __syncthreads();
    }
#pragma unroll
    for (int mi = 0; mi < 4; ++mi)
#pragma unroll
        for (int ni = 0; ni < 4; ++ni)
#pragma unroll
            for (int j = 0; j < 4; ++j) {
                int row = bm * 128 + wr + mi * 16 + lhi * 4 + j;
                int col = bn * 128 + wc + ni * 16 + l15;
                float v = acc[mi][ni][j] + bias[col];
                if (OUTF32)
                    ((float*)Cout)[(size_t)row * N + col] = v;
                else
                    ((bf16*)Cout)[(size_t)row * N + col] = (bf16)v;
            }
}

// ---------------- V transpose: Vp[b*2048+s][g*64+d] -> VT[b][g][d][s] ----------------
__global__ __launch_bounds__(256) void vtrans(const bf16* __restrict__ V,
                                              bf16* __restrict__ VT) {
    __shared__ bf16 t[64][65];
    const int s0 = blockIdx.x * 64;
    const int bg = blockIdx.y;
    const int b = bg >> 2, g = bg & 3;
#pragma unroll
    for (int i = 0; i < 16; ++i) {
        int flat = threadIdx.x + i * 256;
        int r = flat >> 6, c = flat & 63;
        t[c][r] = V[(size_t)(b * S_LEN + s0 + r) * KVD + g * DKH + c];
    }
    __syncthreads();
#pragma unroll
    for (int i = 0; i < 16; ++i) {
        int flat = threadIdx.x + i * 256;
        int d = flat >> 6, si = flat & 63;
        VT[((size_t)bg * DKH + d) * S_LEN + s0 + si] = t[d][si];
    }
}

// ---------------- merged attention v3: single-barrier pass B, PV lag-1 ----------------
// grid 2048 (XCD-swizzled) = bh(32) x qt(64: 32 q-rows); block 512 = 8 waves (2 wq x 4 wk).
// Pass A: staged denominators (K ring-4) as in R10.
// Pass B: ONE lgkm-barrier/chunk; Pb ring-2 (P(c) write || P(c-1) store+PV); K ring-2, V ring-3.
__global__ __launch_bounds__(512, 4) void attn_all(const bf16* __restrict__ Qp,
                                                   const bf16* __restrict__ Kp,
                                                   const bf16* __restrict__ VT,
                                                   float* __restrict__ attn_out,
                                                   bf16* __restrict__ ctx) {
    __shared__ bf16 KV[5][4096];  // 40 KB: pass A = K ring4 (0..3); pass B = K{0,1}, V{2,3,4}
    __shared__ bf16 Pb[2][2048];  // 8 KB [32 q][64 k] bf16 swizzled, ring-2; head = red scratch
    const int raw = blockIdx.x;
    const int wg = (raw & 7) * 256 + (raw >> 3);  // 2048 % 8 == 0: bijective
    const int bh = wg >> 6;
    const int qt = wg & 63;
    const int h = bh & (NH - 1), b = bh >> 4, g = h >> 2;
    const int tid = threadIdx.x, wave = tid >> 6, lane = tid & 63;
    const int l15 = lane & 15, lhi = lane >> 4;
    const int wq = wave >> 2, wk = wave & 3;  // wk doubles as dv-tile in PV
    const int qrow0 = qt * 32;
    const int sw = (l15 & 7) << 4;

    // Q fragments for this wave's 16 q-rows
    const bf16* qb =
        Qp + (size_t)(b * S_LEN + qrow0 + wq * 16 + l15) * DMODEL + h * DKH + lhi * 8;
    bf16x8 aq0 = *(const bf16x8_a*)qb;
    bf16x8 aq1 = *(const bf16x8_a*)(qb + 32);

    // staging: thread -> (row tid>>3, 16B slot tid&7), source slot pre-swizzled
    const int srow = tid >> 3;
    const int scc = (tid & 7) ^ (srow & 7);
    const bf16* ksrc = Kp + (size_t)(b * S_LEN + srow) * KVD + g * DKH + scc * 8;
    const bf16* vsrc = VT + ((size_t)(b * NKVH + g) * DKH + srow) * S_LEN + scc * 8;

    // ================= pass A: denominators (K ring-4, as R10) =================
    gll16(ksrc, &KV[0][wave * 512]);
    gll16(ksrc + (size_t)64 * KVD, &KV[1][wave * 512]);
    float lsum = 0.f;
    for (int c = 0; c < 32; ++c) {
        if (c < 30) gll16(ksrc + (size_t)((c + 2) * 64) * KVD, &KV[(c + 2) & 3][wave * 512]);
        if (c < 30) { VWAIT(2); } else if (c == 30) { VWAIT(1); } else { VWAIT(0); }
        __builtin_amdgcn_s_barrier();
        const char* kc = (const char*)&KV[c & 3][0];
        const int rb = (wk * 16 + l15) * 128;
        bf16x8 k0 = *(const bf16x8_a*)(kc + rb + ((lhi * 16) ^ sw));
        bf16x8 k1 = *(const bf16x8_a*)(kc + rb + ((lhi * 16 + 64) ^ sw));
        f32x4 a = {0.f, 0.f, 0.f, 0.f};
        __builtin_amdgcn_s_setprio(1);
        a = __builtin_amdgcn_mfma_f32_16x16x32_bf16(k0, aq0, a, 0, 0, 0);
        a = __builtin_amdgcn_mfma_f32_16x16x32_bf16(k1, aq1, a, 0, 0, 0);
        __builtin_amdgcn_s_setprio(0);
        lsum += __builtin_exp2f(a[0] * SCALE_LOG2E) + __builtin_exp2f(a[1] * SCALE_LOG2E) +
                __builtin_exp2f(a[2] * SCALE_LOG2E) + __builtin_exp2f(a[3] * SCALE_LOG2E);
    }
    lsum += __shfl_xor(lsum, 16, 64);
    lsum += __shfl_xor(lsum, 32, 64);

    // pass-B prologue staging (lands during reduction barriers): K(0)->KV[0], V(0)->KV[2]
    gll16(ksrc, &KV[0][wave * 512]);
    gll16(vsrc, &KV[2][wave * 512]);

    float* red = (float*)&Pb[0][0];  // 512 B scratch
    if (lane < 16) red[wave * 16 + lane] = lsum;
    LGKM0_BARRIER();  // red visible
    float lt = red[(wq * 4 + 0) * 16 + l15] + red[(wq * 4 + 1) * 16 + l15] +
               red[(wq * 4 + 2) * 16 + l15] + red[(wq * 4 + 3) * 16 + l15];
    const float rinv = 1.0f / lt;
    LGKM0_BARRIER();  // red reads drained before Pb[0] reuse

    // ================= pass B: ONE barrier per chunk =================
    f32x4 cacc = {0.f, 0.f, 0.f, 0.f};
    float* arow = attn_out + ((size_t)bh * S_LEN + qrow0) * S_LEN;
    char* pbb0 = (char*)&Pb[0][0];
    char* pbb1 = (char*)&Pb[1][0];
    const int ql = wq * 16 + l15;                         // q-row this lane produces
    const int pbw = (ql * 128 + wk * 32 + lhi * 8) ^ sw;  // P write byte (within buffer)
    const int strow = tid >> 4;                           // 0..31 store row
    const int stslot = tid & 15;
    const int pbr = (strow * 128 + stslot * 8) ^ ((strow & 7) << 4);  // P read byte
    float* gst = arow + (size_t)strow * S_LEN + stslot * 4;

    for (int c = 0; c < 32; ++c) {
        // outstanding: K(c), V(c) [oldest], then store(c-2) -> VWAIT(1) retires K,V only
        if (c == 0) { VWAIT(0); } else { VWAIT(1); }
        LGKM0_BARRIER();  // K(c),V(c) resident; P(c-1) visible; V/P buffers reusable
        if (c < 31) {
            gll16(ksrc + (size_t)((c + 1) * 64) * KVD, &KV[(c + 1) & 1][wave * 512]);
            gll16(vsrc + (c + 1) * 64, &KV[2 + ((c + 1) % 3)][wave * 512]);
            __builtin_amdgcn_sched_barrier(0);  // keep the prob store AFTER the gll16s
        }
        // QK(c): S[key = c*64 + wk*16 + lhi*4 + j][q = wq*16 + l15]
        const char* kc = (const char*)&KV[c & 1][0];
        const int rb = (wk * 16 + l15) * 128;
        bf16x8 k0 = *(const bf16x8_a*)(kc + rb + ((lhi * 16) ^ sw));
        bf16x8 k1 = *(const bf16x8_a*)(kc + rb + ((lhi * 16 + 64) ^ sw));
        f32x4 a = {0.f, 0.f, 0.f, 0.f};
        __builtin_amdgcn_s_setprio(1);
        a = __builtin_amdgcn_mfma_f32_16x16x32_bf16(k0, aq0, a, 0, 0, 0);
        a = __builtin_amdgcn_mfma_f32_16x16x32_bf16(k1, aq1, a, 0, 0, 0);
        __builtin_amdgcn_s_setprio(0);
        // P(c) -> Pb[c&1] (normalized)
        bf16x4 pb4;
#pragma unroll
        for (int j = 0; j < 4; ++j)
            pb4[j] = (bf16)(__builtin_exp2f(a[j] * SCALE_LOG2E) * rinv);
        *(bf16x4_a*)((c & 1 ? pbb1 : pbb0) + pbw) = pb4;
        if (c > 0) {
            char* pprev = (c & 1) ? pbb0 : pbb1;
            // prob store (c-1): re-read Pb row, widen, 256B-contig per 16-lane group
            bf16x4 pv4 = *(const bf16x4_a*)(pprev + pbr);
            f32x4 pf4;
#pragma unroll
            for (int j = 0; j < 4; ++j) pf4[j] = (float)pv4[j];
            *(f32x4g*)(gst + (c - 1) * 64) = pf4;
            // PV(c-1): A = P(c-1), B = V(c-1) tile
            bf16x8 ap0 = *(const bf16x8_a*)(pprev + ((ql * 128 + lhi * 16) ^ sw));
            bf16x8 ap1 = *(const bf16x8_a*)(pprev + ((ql * 128 + 64 + lhi * 16) ^ sw));
            const char* vc = (const char*)&KV[2 + ((c - 1) % 3)][0];
            const int vb = (wk * 16 + l15) * 128;
            bf16x8 v0 = *(const bf16x8_a*)(vc + vb + ((lhi * 16) ^ sw));
            bf16x8 v1 = *(const bf16x8_a*)(vc + vb + ((lhi * 16 + 64) ^ sw));
            __builtin_amdgcn_s_setprio(1);
            cacc = __builtin_amdgcn_mfma_f32_16x16x32_bf16(ap0, v0, cacc, 0, 0, 0);
            cacc = __builtin_amdgcn_mfma_f32_16x16x32_bf16(ap1, v1, cacc, 0, 0, 0);
            __builtin_amdgcn_s_setprio(0);
        }
    }
    // epilogue: store + PV for chunk 31 (P(31) in Pb[1], V(31) in KV[2 + 31%3 = 3])
    LGKM0_BARRIER();
    {
        bf16x4 pv4 = *(const bf16x4_a*)(pbb1 + pbr);
        f32x4 pf4;
#pragma unroll
        for (int j = 0; j < 4; ++j) pf4[j] = (float)pv4[j];
        *(f32x4g*)(gst + 31 * 64) = pf4;
        bf16x8 ap0 = *(const bf16x8_a*)(pbb1 + ((ql * 128 + lhi * 16) ^ sw));
        bf16x8 ap1 = *(const bf16x8_a*)(pbb1 + ((ql * 128 + 64 + lhi * 16) ^ sw));
        const char* vc = (const char*)&KV[2 + (31 % 3)][0];
        const int vb = (wk * 16 + l15) * 128;
        bf16x8 v0 = *(const bf16x8_a*)(vc + vb + ((lhi * 16) ^ sw));
        bf16x8 v1 = *(const bf16x8_a*)(vc + vb + ((lhi * 16 + 64) ^ sw));
        cacc = __builtin_amdgcn_mfma_f32_16x16x32_bf16(ap0, v0, cacc, 0, 0, 0);
        cacc = __builtin_amdgcn_mfma_f32_16x16x32_bf16(ap1, v1, cacc, 0, 0, 0);
    }
    // ctx write: q = qrow0 + wq*16 + lhi*4 + j, dv = h*64 + wk*16 + l15 (P pre-normalized)
#pragma unroll
    for (int j = 0; j < 4; ++j) {
        int row = qrow0 + wq * 16 + lhi * 4 + j;
        ctx[(size_t)(b * S_LEN + row) * DMODEL + h * DKH + wk * 16 + l15] = (bf16)cacc[j];
    }
}

extern "C" void kernel_launch(void* const* d_in, const int* in_sizes, int n_in,
                              void* d_out, int out_size, void* d_ws, size_t ws_size,
                              hipStream_t stream) {
    const float* query = (const float*)d_in[0];
    const float* key_i = (const float*)d_in[1];
    const float* value = (const float*)d_in[2];
    const float* Wq = (const float*)d_in[3];
    const float* bq = (const float*)d_in[4];
    const float* Wk = (const float*)d_in[5];
    const float* bk = (const float*)d_in[6];
    const float* Wv = (const float*)d_in[7];
    const float* bv = (const float*)d_in[8];
    const float* Wo = (const float*)d_in[9];
    const float* bo = (const float*)d_in[10];

    char* ws = (char*)d_ws;
    bf16* qx = (bf16*)(ws + 0);
    bf16* kx = (bf16*)(ws + ((size_t)8 << 20));
    bf16* vx = (bf16*)(ws + ((size_t)16 << 20));
    bf16* wqx = (bf16*)(ws + ((size_t)32 << 20));
    bf16* wkx = (bf16*)(ws + ((size_t)34 << 20));
    bf16* wvx = (bf16*)(ws + ((size_t)34 << 20) + ((size_t)512 << 10));
    bf16* wox = (bf16*)(ws + ((size_t)35 << 20));
    bf16* Qp = (bf16*)(ws + ((size_t)37 << 20));
    bf16* Kp = (bf16*)(ws + ((size_t)45 << 20));
    bf16* Vp = (bf16*)(ws + ((size_t)47 << 20));
    bf16* VT = (bf16*)(ws + ((size_t)49 << 20));
    bf16* ctxb = (bf16*)(ws + ((size_t)51 << 20));

    const int BS = 2 * S_LEN;  // 4096 rows

    cast3_bf16<<<dim3(1024, 3), 256, 0, stream>>>(query, key_i, value, qx, kx, vx,
                                                  BS * DMODEL / 4);
    cast2_bf16<<<dim3(1024, 2), 256, 0, stream>>>(Wq, Wo, wqx, wox, DMODEL * DMODEL / 4);
    cast2_bf16<<<dim3(256, 2), 256, 0, stream>>>(Wk, Wv, wkx, wvx, KVD * DMODEL / 4);

    gemm_bt<0><<<dim3(32, 8), 256, 0, stream>>>(qx, wqx, bq, Qp, BS, DMODEL, DMODEL);
    gemm_bt<0><<<dim3(32, 2), 256, 0, stream>>>(kx, wkx, bk, Kp, BS, KVD, DMODEL);
    gemm_bt<0><<<dim3(32, 2), 256, 0, stream>>>(vx, wvx, bv, Vp, BS, KVD, DMODEL);

    vtrans<<<dim3(32, 8), 256, 0, stream>>>(Vp, VT);

    float* attn_out = (float*)d_out + (size_t)BS * DMODEL;
    attn_all<<<2048, 512, 0, stream>>>(Qp, Kp, VT, attn_out, ctxb);

    gemm_bt<1><<<dim3(32, 8), 256, 0, stream>>>(ctxb, wox, bo, (float*)d_out, BS, DMODEL, DMODEL);
}